// Round 3
// baseline (220.301 us; speedup 1.0000x reference)
//
#include <hip/hip_runtime.h>

// Problem constants: B=1, S=4096, D=1024, H=16, W=512, HD=64, C=8 chunks.
typedef __attribute__((ext_vector_type(8))) short short8;
typedef __attribute__((ext_vector_type(4))) float f32x4;
typedef unsigned short u16;

__device__ __forceinline__ u16 f2bf(float f) {
  unsigned int u = __float_as_uint(f);
  u += 0x7fffu + ((u >> 16) & 1u);   // round-to-nearest-even
  return (u16)(u >> 16);
}

// async global->LDS, 16B per lane. LDS dest = wave-uniform base + lane*16.
__device__ __forceinline__ void gld16(const void* g, void* l) {
  __builtin_amdgcn_global_load_lds((const __attribute__((address_space(1))) void*)g,
                                   (__attribute__((address_space(3))) void*)l, 16, 0, 0);
}

// ---------------- cast f32 -> bf16 (8 elems/thread) ----------------
__global__ __launch_bounds__(256) void cast_f32_to_bf16(const float* __restrict__ in,
                                                        u16* __restrict__ out, int n8) {
  int i = blockIdx.x * 256 + threadIdx.x;
  if (i >= n8) return;
  const f32x4* p = (const f32x4*)in;
  f32x4 a = p[i * 2];
  f32x4 b = p[i * 2 + 1];
  short8 o;
#pragma unroll
  for (int j = 0; j < 4; ++j) o[j] = (short)f2bf(a[j]);
#pragma unroll
  for (int j = 0; j < 4; ++j) o[4 + j] = (short)f2bf(b[j]);
  ((short8*)out)[i] = o;
}

// ---------------- transpose [K][N] f32 -> [N][K] bf16 ----------------
__global__ __launch_bounds__(256) void transpose_cast(const float* __restrict__ w,
                                                      u16* __restrict__ wT, int K, int N) {
  __shared__ float tile[32][33];
  int n0 = blockIdx.x * 32, k0 = blockIdx.y * 32;
  int r = threadIdx.x >> 5;   // 0..7
  int c = threadIdx.x & 31;
#pragma unroll
  for (int i = 0; i < 4; ++i)
    tile[r + i * 8][c] = w[(size_t)(k0 + r + i * 8) * N + n0 + c];
  __syncthreads();
#pragma unroll
  for (int i = 0; i < 4; ++i)
    wT[(size_t)(n0 + r + i * 8) * K + k0 + c] = f2bf(tile[c][r + i * 8]);
}

// ---------------- bf16 MFMA GEMM (m97 structure): C = A[M][K] * Bt[N][K]^T ----------------
// BK=64, linear LDS, global_load_lds width-16, 2 barriers per K-step.
// MODE 0: write f32 to C row-major.
// MODE 1: split cols into q/k/v and write bf16 in [H=16][S=4096][64] head layout.
template <int MODE>
__global__ __launch_bounds__(256) void gemm_bf16(
    const u16* __restrict__ A, const u16* __restrict__ Bt, float* __restrict__ C,
    u16* __restrict__ q_out, u16* __restrict__ k_out, u16* __restrict__ v_out,
    int M, int N, int K) {
  __shared__ __align__(16) u16 As[128][64];
  __shared__ __align__(16) u16 Bs[128][64];
  const int t = threadIdx.x;
  const int lane = t & 63;
  const int wid = t >> 6;
  const int wm = wid >> 1, wn = wid & 1;  // 2x2 waves, 64x64 each
  const int l15 = lane & 15, lhi = lane >> 4;
  const int m0 = blockIdx.y * 128;
  const int n0 = blockIdx.x * 128;
  const int srow = lane >> 3;           // staging row within 8-row chunk
  const int scol = (lane & 7) * 8;      // staging col (shorts)

  f32x4 acc[4][4];
#pragma unroll
  for (int mi = 0; mi < 4; ++mi)
#pragma unroll
    for (int ni = 0; ni < 4; ++ni) acc[mi][ni] = (f32x4){0.f, 0.f, 0.f, 0.f};

  for (int k0 = 0; k0 < K; k0 += 64) {
    __syncthreads();  // readers done with LDS
#pragma unroll
    for (int i = 0; i < 4; ++i) {
      int cch = wid * 4 + i;            // 16 chunks x 1KB per matrix
      int row = cch * 8 + srow;
      gld16(&A[(size_t)(m0 + row) * K + k0 + scol], &As[cch * 8][0]);
      gld16(&Bt[(size_t)(n0 + row) * K + k0 + scol], &Bs[cch * 8][0]);
    }
    __syncthreads();  // compiler drains vmcnt(0) before barrier
#pragma unroll
    for (int kc = 0; kc < 2; ++kc) {
      short8 af[4], bf[4];
#pragma unroll
      for (int mi = 0; mi < 4; ++mi)
        af[mi] = *(const short8*)&As[wm * 64 + mi * 16 + l15][kc * 32 + lhi * 8];
#pragma unroll
      for (int ni = 0; ni < 4; ++ni)
        bf[ni] = *(const short8*)&Bs[wn * 64 + ni * 16 + l15][kc * 32 + lhi * 8];
#pragma unroll
      for (int mi = 0; mi < 4; ++mi)
#pragma unroll
        for (int ni = 0; ni < 4; ++ni)
          acc[mi][ni] = __builtin_amdgcn_mfma_f32_16x16x32_bf16(af[mi], bf[ni], acc[mi][ni], 0, 0, 0);
    }
  }

  // epilogue; C/D layout: col = lane&15, row = (lane>>4)*4 + reg  [HW-verified]
#pragma unroll
  for (int mi = 0; mi < 4; ++mi)
#pragma unroll
    for (int ni = 0; ni < 4; ++ni)
#pragma unroll
      for (int r = 0; r < 4; ++r) {
        int row = m0 + wm * 64 + mi * 16 + lhi * 4 + r;
        int col = n0 + wn * 64 + ni * 16 + l15;
        float val = acc[mi][ni][r];
        if (MODE == 0) {
          C[(size_t)row * N + col] = val;
        } else {
          int which = col >> 10;           // 0:q 1:k 2:v
          int d = col & 1023;
          int hh = d >> 6, hd = d & 63;
          u16* dst = (which == 0) ? q_out : ((which == 1) ? k_out : v_out);
          dst[((size_t)hh * 4096 + row) * 64 + hd] = f2bf(val);
        }
      }
}

// ---------------- sliding-window flash attention ----------------
// Grid: 512 blocks (XCD-chunked swizzle). Block: 4 waves, each owns 32 queries.
// Per (h,c): Q[512][64] attends to keys j in [0,1024) = [prev chunk | cur chunk].
// K tile staged via global_load_lds with pre-swizzled source (unit ^= row&7 on read).
// V^T tile reg-transposed with XOR-swizzled writes (col ^= ((d>>3 ^ d)&7)<<3).
__global__ __launch_bounds__(256) void attn_kernel(
    const u16* __restrict__ qh,   // [16][4096][64] bf16
    const u16* __restrict__ kh,
    const u16* __restrict__ vh,
    u16* __restrict__ out) {      // [4096][1024] bf16
  __shared__ __align__(16) u16 Ks[64][64];        // 8KB, swizzled storage
  __shared__ __align__(16) u16 Vt[64][64];        // 8KB, [d][key] swizzled
  __shared__ __align__(16) u16 Pl[4][32][72];     // 18KB per-wave P tiles

  const int t = threadIdx.x;
  const int lane = t & 63;
  const int w = t >> 6;
  const int l15 = lane & 15;
  const int lhi = lane >> 4;

  // XCD-chunked swizzle: XCD x serves works [x*64, (x+1)*64) = heads {2x, 2x+1}
  const int bid = blockIdx.x;
  const int wk = (bid & 7) * 64 + (bid >> 3);
  const int qt = wk & 3, c = (wk >> 2) & 7, h = wk >> 5;

  const long head_base = (long)h * 4096 * 64;
  const int q0 = qt * 128;  // query offset within chunk
  const long q_gbase = head_base + (long)(c * 512 + q0) * 64;

  // Q fragments straight to registers (read once; no LDS round-trip)
  short8 qf[2][2];
#pragma unroll
  for (int mi = 0; mi < 2; ++mi)
#pragma unroll
    for (int kc = 0; kc < 2; ++kc)
      qf[mi][kc] = *(const short8*)&qh[q_gbase + (long)(w * 32 + mi * 16 + l15) * 64 + kc * 32 + lhi * 8];

  float m_run[8], l_run[8];  // idx mi*4+r ; q-row = q0 + w*32 + mi*16 + lhi*4 + r
  f32x4 acc_o[2][4];
#pragma unroll
  for (int i = 0; i < 8; ++i) { m_run[i] = -1e30f; l_run[i] = 0.f; }
#pragma unroll
  for (int mi = 0; mi < 2; ++mi)
#pragma unroll
    for (int ni = 0; ni < 4; ++ni) acc_o[mi][ni] = (f32x4){0.f, 0.f, 0.f, 0.f};

  const int kt_start = (c == 0) ? 8 : 0;     // chunk 0: no prev chunk
  const int kt_end = 2 * qt + 9;             // causal trim: j_max = qt*128+639
  const long kv_base = head_base + ((long)c - 1) * 512 * 64;  // j=0 -> key (c-1)*512

  const int ksrow = lane >> 3;                           // 0..7 within chunk
  const int kscol = ((lane & 7) ^ (lane >> 3)) * 8;      // pre-swizzled source unit

  for (int kt = kt_start; kt <= kt_end; ++kt) {
    const int j0 = kt * 64;
    __syncthreads();  // prior tile's LDS reads done
    // K: 8 x 1KB chunks via global_load_lds, source pre-swizzled so that
    // physical Ks[r][u] holds logical unit u^(r&7).
#pragma unroll
    for (int i = 0; i < 2; ++i) {
      int cch = w * 2 + i;
      int row = cch * 8 + ksrow;
      gld16(&kh[kv_base + (long)(j0 + row) * 64 + kscol], &Ks[cch * 8][0]);
    }
    // V: reg-transpose, XOR-swizzled scalar writes (conflict-free)
#pragma unroll
    for (int i = 0; i < 2; ++i) {
      int slot = i * 256 + t;
      int r = slot >> 3, g = slot & 7;
      short8 vv = *(const short8*)&vh[kv_base + (long)(j0 + r) * 64 + g * 8];
#pragma unroll
      for (int j = 0; j < 8; ++j)
        Vt[g * 8 + j][r ^ ((g ^ j) << 3)] = (u16)vv[j];
    }
    __syncthreads();

    // QK^T: 32 queries x 64 keys per wave
    f32x4 sa[2][4];
#pragma unroll
    for (int mi = 0; mi < 2; ++mi)
#pragma unroll
      for (int ni = 0; ni < 4; ++ni) sa[mi][ni] = (f32x4){0.f, 0.f, 0.f, 0.f};
#pragma unroll
    for (int kc = 0; kc < 2; ++kc) {
      short8 kf[4];
#pragma unroll
      for (int ni = 0; ni < 4; ++ni) {
        int row = ni * 16 + l15;
        int colu = (kc * 4 + lhi) ^ (row & 7);   // swizzled 16B-unit
        kf[ni] = *(const short8*)&Ks[row][colu * 8];
      }
#pragma unroll
      for (int mi = 0; mi < 2; ++mi)
#pragma unroll
        for (int ni = 0; ni < 4; ++ni)
          sa[mi][ni] = __builtin_amdgcn_mfma_f32_16x16x32_bf16(qf[mi][kc], kf[ni], sa[mi][ni], 0, 0, 0);
    }

    // scale + causal mask + online softmax
    const int qrow0 = q0 + w * 32 + lhi * 4;
    float tmax[8];
#pragma unroll
    for (int i = 0; i < 8; ++i) tmax[i] = -1e30f;
#pragma unroll
    for (int mi = 0; mi < 2; ++mi)
#pragma unroll
      for (int ni = 0; ni < 4; ++ni) {
        int jj = j0 + ni * 16 + l15;
#pragma unroll
        for (int r = 0; r < 4; ++r) {
          float sv = sa[mi][ni][r] * 0.125f;
          int qq = qrow0 + mi * 16 + r;
          sv = (qq + 512 >= jj) ? sv : -1e30f;
          sa[mi][ni][r] = sv;
          tmax[mi * 4 + r] = fmaxf(tmax[mi * 4 + r], sv);
        }
      }
#pragma unroll
    for (int i = 0; i < 8; ++i)
#pragma unroll
      for (int d = 1; d < 16; d <<= 1)
        tmax[i] = fmaxf(tmax[i], __shfl_xor(tmax[i], d, 64));

    float corr[8], rsum[8];
#pragma unroll
    for (int i = 0; i < 8; ++i) {
      float mn = fmaxf(m_run[i], tmax[i]);
      corr[i] = __expf(m_run[i] - mn);
      m_run[i] = mn;
      rsum[i] = 0.f;
    }
#pragma unroll
    for (int mi = 0; mi < 2; ++mi)
#pragma unroll
      for (int ni = 0; ni < 4; ++ni)
#pragma unroll
        for (int r = 0; r < 4; ++r) {
          float p = __expf(sa[mi][ni][r] - m_run[mi * 4 + r]);
          rsum[mi * 4 + r] += p;
          Pl[w][mi * 16 + lhi * 4 + r][ni * 16 + l15] = f2bf(p);
        }
#pragma unroll
    for (int i = 0; i < 8; ++i) {
#pragma unroll
      for (int d = 1; d < 16; d <<= 1) rsum[i] += __shfl_xor(rsum[i], d, 64);
      l_run[i] = l_run[i] * corr[i] + rsum[i];
    }
#pragma unroll
    for (int mi = 0; mi < 2; ++mi)
#pragma unroll
      for (int ni = 0; ni < 4; ++ni)
#pragma unroll
        for (int r = 0; r < 4; ++r) acc_o[mi][ni][r] *= corr[mi * 4 + r];

    // PV: O[32][64] += P[32][64] * V[64][64]  (Vt reads de-swizzled)
#pragma unroll
    for (int k2 = 0; k2 < 2; ++k2) {
      short8 pf[2];
#pragma unroll
      for (int mi = 0; mi < 2; ++mi)
        pf[mi] = *(const short8*)&Pl[w][mi * 16 + l15][k2 * 32 + lhi * 8];
#pragma unroll
      for (int ni = 0; ni < 4; ++ni) {
        int row = ni * 16 + l15;
        int S = ((row >> 3) ^ row) & 7;
        short8 vf = *(const short8*)&Vt[row][(k2 * 32 + lhi * 8) ^ (S << 3)];
#pragma unroll
        for (int mi = 0; mi < 2; ++mi)
          acc_o[mi][ni] = __builtin_amdgcn_mfma_f32_16x16x32_bf16(pf[mi], vf, acc_o[mi][ni], 0, 0, 0);
      }
    }
  }

  // normalize + write [S][D] bf16 (head-interleaved cols)
#pragma unroll
  for (int mi = 0; mi < 2; ++mi)
#pragma unroll
    for (int ni = 0; ni < 4; ++ni)
#pragma unroll
      for (int r = 0; r < 4; ++r) {
        int qq = q0 + w * 32 + mi * 16 + lhi * 4 + r;
        long s = (long)c * 512 + qq;
        int col = h * 64 + ni * 16 + l15;
        float o = acc_o[mi][ni][r] / l_run[mi * 4 + r];
        out[s * 1024 + col] = f2bf(o);
      }
}

extern "C" void kernel_launch(void* const* d_in, const int* in_sizes, int n_in,
                              void* d_out, int out_size, void* d_ws, size_t ws_size,
                              hipStream_t stream) {
  const float* x = (const float*)d_in[0];      // [4096][1024]
  const float* w_qkv = (const float*)d_in[1];  // [1024][3072]
  const float* w_out = (const float*)d_in[2];  // [1024][1024]
  float* out = (float*)d_out;                  // [4096][1024]

  u16* xb = (u16*)d_ws;                        // 4096*1024
  u16* wqkvT = xb + 4096 * 1024;               // [3072][1024]
  u16* woutT = wqkvT + 3072 * 1024;            // [1024][1024]
  u16* qh = woutT + 1024 * 1024;               // [16][4096][64]
  u16* kh = qh + 16 * 4096 * 64;
  u16* vh = kh + 16 * 4096 * 64;
  u16* attn = xb;  // alias: x_bf16 dead after GEMM1  (total ws = 40 MB)

  cast_f32_to_bf16<<<2048, 256, 0, stream>>>(x, xb, 4096 * 1024 / 8);
  transpose_cast<<<dim3(96, 32), 256, 0, stream>>>(w_qkv, wqkvT, 1024, 3072);
  transpose_cast<<<dim3(32, 32), 256, 0, stream>>>(w_out, woutT, 1024, 1024);

  gemm_bf16<1><<<dim3(24, 32), 256, 0, stream>>>(xb, wqkvT, nullptr, qh, kh, vh,
                                                 4096, 3072, 1024);
  attn_kernel<<<512, 256, 0, stream>>>(qh, kh, vh, attn);
  gemm_bf16<0><<<dim3(8, 32), 256, 0, stream>>>(attn, woutT, out, nullptr, nullptr, nullptr,
                                                4096, 1024, 1024);
}

// Round 4
// 213.739 us; speedup vs baseline: 1.0307x; 1.0307x over previous
//
#include <hip/hip_runtime.h>

// Problem constants: B=1, S=4096, D=1024, H=16, W=512, HD=64, C=8 chunks.
typedef __attribute__((ext_vector_type(8))) short short8;
typedef __attribute__((ext_vector_type(4))) float f32x4;
typedef unsigned short u16;

__device__ __forceinline__ u16 f2bf(float f) {
  unsigned int u = __float_as_uint(f);
  u += 0x7fffu + ((u >> 16) & 1u);   // round-to-nearest-even
  return (u16)(u >> 16);
}

// async global->LDS, 16B per lane. LDS dest = wave-uniform base + lane*16.
__device__ __forceinline__ void gld16(const void* g, void* l) {
  __builtin_amdgcn_global_load_lds((const __attribute__((address_space(1))) void*)g,
                                   (__attribute__((address_space(3))) void*)l, 16, 0, 0);
}

// ---------------- cast f32 -> bf16 (8 elems/thread) ----------------
__global__ __launch_bounds__(256) void cast_f32_to_bf16(const float* __restrict__ in,
                                                        u16* __restrict__ out, int n8) {
  int i = blockIdx.x * 256 + threadIdx.x;
  if (i >= n8) return;
  const f32x4* p = (const f32x4*)in;
  f32x4 a = p[i * 2];
  f32x4 b = p[i * 2 + 1];
  short8 o;
#pragma unroll
  for (int j = 0; j < 4; ++j) o[j] = (short)f2bf(a[j]);
#pragma unroll
  for (int j = 0; j < 4; ++j) o[4 + j] = (short)f2bf(b[j]);
  ((short8*)out)[i] = o;
}

// ---------------- transpose [K][N] f32 -> [N][K] bf16 ----------------
__global__ __launch_bounds__(256) void transpose_cast(const float* __restrict__ w,
                                                      u16* __restrict__ wT, int K, int N) {
  __shared__ float tile[32][33];
  int n0 = blockIdx.x * 32, k0 = blockIdx.y * 32;
  int r = threadIdx.x >> 5;   // 0..7
  int c = threadIdx.x & 31;
#pragma unroll
  for (int i = 0; i < 4; ++i)
    tile[r + i * 8][c] = w[(size_t)(k0 + r + i * 8) * N + n0 + c];
  __syncthreads();
#pragma unroll
  for (int i = 0; i < 4; ++i)
    wT[(size_t)(n0 + r + i * 8) * K + k0 + c] = f2bf(tile[c][r + i * 8]);
}

// ---------------- bf16 MFMA GEMM (m97 structure): C = A[M][K] * Bt[N][K]^T ----------------
// BK=64, linear LDS, global_load_lds width-16, 2 barriers per K-step, XCD swizzle.
template <int MODE>
__global__ __launch_bounds__(256) void gemm_bf16(
    const u16* __restrict__ A, const u16* __restrict__ Bt, float* __restrict__ C,
    u16* __restrict__ q_out, u16* __restrict__ k_out, u16* __restrict__ v_out,
    int M, int N, int K) {
  __shared__ __align__(16) u16 As[128][64];
  __shared__ __align__(16) u16 Bs[128][64];
  const int t = threadIdx.x;
  const int lane = t & 63;
  const int wid = t >> 6;
  const int wm = wid >> 1, wn = wid & 1;  // 2x2 waves, 64x64 each
  const int l15 = lane & 15, lhi = lane >> 4;

  // XCD-chunked bijective swizzle (grid size % 8 == 0 for both call sites)
  const int nbx = gridDim.x;
  const int bid = blockIdx.y * nbx + blockIdx.x;
  const int cpx = (nbx * gridDim.y) >> 3;
  const int wg = (bid & 7) * cpx + (bid >> 3);
  const int m0 = (wg / nbx) * 128;
  const int n0 = (wg % nbx) * 128;

  const int srow = lane >> 3;           // staging row within 8-row chunk
  const int scol = (lane & 7) * 8;      // staging col (shorts)

  f32x4 acc[4][4];
#pragma unroll
  for (int mi = 0; mi < 4; ++mi)
#pragma unroll
    for (int ni = 0; ni < 4; ++ni) acc[mi][ni] = (f32x4){0.f, 0.f, 0.f, 0.f};

  for (int k0 = 0; k0 < K; k0 += 64) {
    __syncthreads();  // readers done with LDS
#pragma unroll
    for (int i = 0; i < 4; ++i) {
      int cch = wid * 4 + i;            // 16 chunks x 1KB per matrix
      int row = cch * 8 + srow;
      gld16(&A[(size_t)(m0 + row) * K + k0 + scol], &As[cch * 8][0]);
      gld16(&Bt[(size_t)(n0 + row) * K + k0 + scol], &Bs[cch * 8][0]);
    }
    __syncthreads();  // compiler drains vmcnt(0) before barrier
#pragma unroll
    for (int kc = 0; kc < 2; ++kc) {
      short8 af[4], bf[4];
#pragma unroll
      for (int mi = 0; mi < 4; ++mi)
        af[mi] = *(const short8*)&As[wm * 64 + mi * 16 + l15][kc * 32 + lhi * 8];
#pragma unroll
      for (int ni = 0; ni < 4; ++ni)
        bf[ni] = *(const short8*)&Bs[wn * 64 + ni * 16 + l15][kc * 32 + lhi * 8];
#pragma unroll
      for (int mi = 0; mi < 4; ++mi)
#pragma unroll
        for (int ni = 0; ni < 4; ++ni)
          acc[mi][ni] = __builtin_amdgcn_mfma_f32_16x16x32_bf16(af[mi], bf[ni], acc[mi][ni], 0, 0, 0);
    }
  }

  // epilogue; C/D layout: col = lane&15, row = (lane>>4)*4 + reg  [HW-verified]
#pragma unroll
  for (int mi = 0; mi < 4; ++mi)
#pragma unroll
    for (int ni = 0; ni < 4; ++ni)
#pragma unroll
      for (int r = 0; r < 4; ++r) {
        int row = m0 + wm * 64 + mi * 16 + lhi * 4 + r;
        int col = n0 + wn * 64 + ni * 16 + l15;
        float val = acc[mi][ni][r];
        if (MODE == 0) {
          C[(size_t)row * N + col] = val;
        } else {
          int which = col >> 10;           // 0:q 1:k 2:v
          int d = col & 1023;
          int hh = d >> 6, hd = d & 63;
          u16* dst = (which == 0) ? q_out : ((which == 1) ? k_out : v_out);
          dst[((size_t)hh * 4096 + row) * 64 + hd] = f2bf(val);
        }
      }
}

// ---------------- sliding-window flash attention ----------------
// Grid: 512 blocks (XCD-chunked). Block: 4 waves, each owns 32 queries.
// Double-buffered K/V with async-stage split (T14): next tile's K via
// global_load_lds and V via global->reg issued before current tile's compute.
// Softmax in exp2 domain; denominator l computed by MFMA vs an all-ones V row.
__global__ __launch_bounds__(256) void attn_kernel(
    const u16* __restrict__ qh,   // [16][4096][64] bf16
    const u16* __restrict__ kh,
    const u16* __restrict__ vh,
    u16* __restrict__ out) {      // [4096][1024] bf16
  __shared__ __align__(16) u16 Ks[2][64][64];     // 16KB, swizzled storage
  __shared__ __align__(16) u16 Vt[2][66][64];     // 16.5KB, [d][key]; row 64 = ones
  __shared__ __align__(16) u16 Pl[4][32][72];     // 18KB per-wave P tiles

  const int t = threadIdx.x;
  const int lane = t & 63;
  const int w = t >> 6;
  const int l15 = lane & 15;
  const int lhi = lane >> 4;

  // XCD-chunked swizzle: XCD x serves works [x*64, (x+1)*64) = heads {2x, 2x+1}
  const int bid = blockIdx.x;
  const int wk = (bid & 7) * 64 + (bid >> 3);
  const int qt = wk & 3, c = (wk >> 2) & 7, h = wk >> 5;

  const long head_base = (long)h * 4096 * 64;
  const int q0 = qt * 128;  // query offset within chunk
  const long q_gbase = head_base + (long)(c * 512 + q0) * 64;

  // Q fragments straight to registers
  short8 qf[2][2];
#pragma unroll
  for (int mi = 0; mi < 2; ++mi)
#pragma unroll
    for (int kc = 0; kc < 2; ++kc)
      qf[mi][kc] = *(const short8*)&qh[q_gbase + (long)(w * 32 + mi * 16 + l15) * 64 + kc * 32 + lhi * 8];

  // ones rows (both buffers) for the l-via-MFMA trick: bf16(1.0) = 0x3F80
  if (t < 128) Vt[t >> 6][64][t & 63] = 0x3F80;

  float m_run[8];
  f32x4 acc_o[2][4], acc_l[2];
#pragma unroll
  for (int i = 0; i < 8; ++i) m_run[i] = -1e30f;
#pragma unroll
  for (int mi = 0; mi < 2; ++mi) {
    acc_l[mi] = (f32x4){0.f, 0.f, 0.f, 0.f};
#pragma unroll
    for (int ni = 0; ni < 4; ++ni) acc_o[mi][ni] = (f32x4){0.f, 0.f, 0.f, 0.f};
  }

  const int kt_start = (c == 0) ? 8 : 0;     // chunk 0: no prev chunk
  const int kt_end = 2 * qt + 9;             // causal trim: j_max = qt*128+639
  const long kv_base = head_base + ((long)c - 1) * 512 * 64;  // j=0 -> key (c-1)*512

  const int ksrow = lane >> 3;                           // 0..7 within chunk
  const int kscol = ((lane & 7) ^ (lane >> 3)) * 8;      // pre-swizzled source unit
  const int vr = t >> 3, vg = t & 7;                     // V stage coords (slot 0)

  // prologue: stage tile kt_start into buffer 0
  {
    const int j0 = kt_start * 64;
#pragma unroll
    for (int i = 0; i < 2; ++i) {
      int cch = w * 2 + i;
      gld16(&kh[kv_base + (long)(j0 + cch * 8 + ksrow) * 64 + kscol], &Ks[0][cch * 8][0]);
    }
#pragma unroll
    for (int i = 0; i < 2; ++i) {
      int r = vr + i * 32;
      short8 vv = *(const short8*)&vh[kv_base + (long)(j0 + r) * 64 + vg * 8];
#pragma unroll
      for (int j = 0; j < 8; ++j) Vt[0][vg * 8 + j][r ^ ((vg ^ j) << 3)] = (u16)vv[j];
    }
  }
  __syncthreads();

  int cur = 0;
  for (int kt = kt_start; kt <= kt_end; ++kt) {
    const int j0 = kt * 64;
    const int nxt = cur ^ 1;
    const bool has_next = (kt < kt_end);

    // ---- issue next tile's loads early (latency hides under compute) ----
    short8 vpre[2];
    if (has_next) {
      const int j0n = j0 + 64;
#pragma unroll
      for (int i = 0; i < 2; ++i) {
        int cch = w * 2 + i;
        gld16(&kh[kv_base + (long)(j0n + cch * 8 + ksrow) * 64 + kscol], &Ks[nxt][cch * 8][0]);
      }
#pragma unroll
      for (int i = 0; i < 2; ++i)
        vpre[i] = *(const short8*)&vh[kv_base + (long)(j0n + vr + i * 32) * 64 + vg * 8];
    }

    const bool active = (j0 <= q0 + w * 32 + 31 + 512);  // wave-level causal skip
    if (active) {
      // QK^T: 32 queries x 64 keys per wave
      f32x4 sa[2][4];
#pragma unroll
      for (int mi = 0; mi < 2; ++mi)
#pragma unroll
        for (int ni = 0; ni < 4; ++ni) sa[mi][ni] = (f32x4){0.f, 0.f, 0.f, 0.f};
#pragma unroll
      for (int kc = 0; kc < 2; ++kc) {
        short8 kf[4];
#pragma unroll
        for (int ni = 0; ni < 4; ++ni) {
          int row = ni * 16 + l15;
          int colu = (kc * 4 + lhi) ^ (row & 7);   // swizzled 16B-unit
          kf[ni] = *(const short8*)&Ks[cur][row][colu * 8];
        }
#pragma unroll
        for (int mi = 0; mi < 2; ++mi)
#pragma unroll
          for (int ni = 0; ni < 4; ++ni)
            sa[mi][ni] = __builtin_amdgcn_mfma_f32_16x16x32_bf16(qf[mi][kc], kf[ni], sa[mi][ni], 0, 0, 0);
      }

      // scale (exp2 domain) + mask only on boundary tiles + row max
      const float SC = 0.18033688011112042f;  // 0.125 * log2(e)
      const int qrow0 = q0 + w * 32 + lhi * 4;
      const bool need_mask = (j0 + 63 > q0 + w * 32 + 512);
      float tmax[8];
#pragma unroll
      for (int i = 0; i < 8; ++i) tmax[i] = -1e30f;
      if (need_mask) {
#pragma unroll
        for (int mi = 0; mi < 2; ++mi)
#pragma unroll
          for (int ni = 0; ni < 4; ++ni) {
            int jj = j0 + ni * 16 + l15;
#pragma unroll
            for (int r = 0; r < 4; ++r) {
              float sv = sa[mi][ni][r] * SC;
              sv = (qrow0 + mi * 16 + r + 512 >= jj) ? sv : -1e30f;
              sa[mi][ni][r] = sv;
              tmax[mi * 4 + r] = fmaxf(tmax[mi * 4 + r], sv);
            }
          }
      } else {
#pragma unroll
        for (int mi = 0; mi < 2; ++mi)
#pragma unroll
          for (int ni = 0; ni < 4; ++ni)
#pragma unroll
            for (int r = 0; r < 4; ++r) {
              float sv = sa[mi][ni][r] * SC;
              sa[mi][ni][r] = sv;
              tmax[mi * 4 + r] = fmaxf(tmax[mi * 4 + r], sv);
            }
      }
#pragma unroll
      for (int i = 0; i < 8; ++i)
#pragma unroll
        for (int d = 1; d < 16; d <<= 1)
          tmax[i] = fmaxf(tmax[i], __shfl_xor(tmax[i], d, 64));

      float corr[8];
#pragma unroll
      for (int i = 0; i < 8; ++i) {
        float mn = fmaxf(m_run[i], tmax[i]);
        corr[i] = __builtin_amdgcn_exp2f(m_run[i] - mn);
        m_run[i] = mn;
      }
#pragma unroll
      for (int mi = 0; mi < 2; ++mi)
#pragma unroll
        for (int ni = 0; ni < 4; ++ni)
#pragma unroll
          for (int r = 0; r < 4; ++r) {
            float p = __builtin_amdgcn_exp2f(sa[mi][ni][r] - m_run[mi * 4 + r]);
            Pl[w][mi * 16 + lhi * 4 + r][ni * 16 + l15] = f2bf(p);
          }
#pragma unroll
      for (int mi = 0; mi < 2; ++mi) {
#pragma unroll
        for (int r = 0; r < 4; ++r) acc_l[mi][r] *= corr[mi * 4 + r];
#pragma unroll
        for (int ni = 0; ni < 4; ++ni)
#pragma unroll
          for (int r = 0; r < 4; ++r) acc_o[mi][ni][r] *= corr[mi * 4 + r];
      }
    }

    // ---- write prefetched V into next buffer (all waves; vmcnt waited here) ----
    if (has_next) {
#pragma unroll
      for (int i = 0; i < 2; ++i) {
        int r = vr + i * 32;
#pragma unroll
        for (int j = 0; j < 8; ++j) Vt[nxt][vg * 8 + j][r ^ ((vg ^ j) << 3)] = (u16)vpre[i][j];
      }
    }

    if (active) {
      // PV: O[32][64] += P[32][64] * V[64][64]; l via all-ones row 64
#pragma unroll
      for (int k2 = 0; k2 < 2; ++k2) {
        short8 pf[2];
#pragma unroll
        for (int mi = 0; mi < 2; ++mi)
          pf[mi] = *(const short8*)&Pl[w][mi * 16 + l15][k2 * 32 + lhi * 8];
        short8 vones = *(const short8*)&Vt[cur][64][k2 * 32 + lhi * 8];
#pragma unroll
        for (int mi = 0; mi < 2; ++mi)
          acc_l[mi] = __builtin_amdgcn_mfma_f32_16x16x32_bf16(pf[mi], vones, acc_l[mi], 0, 0, 0);
#pragma unroll
        for (int ni = 0; ni < 4; ++ni) {
          int row = ni * 16 + l15;
          int S = ((row >> 3) ^ row) & 7;
          short8 vf = *(const short8*)&Vt[cur][row][(k2 * 32 + lhi * 8) ^ (S << 3)];
#pragma unroll
          for (int mi = 0; mi < 2; ++mi)
            acc_o[mi][ni] = __builtin_amdgcn_mfma_f32_16x16x32_bf16(pf[mi], vf, acc_o[mi][ni], 0, 0, 0);
        }
      }
    }
    __syncthreads();  // single barrier: cur reads done, nxt writes visible
    cur = nxt;
  }

  // normalize + write [S][D] bf16 (head-interleaved cols)
#pragma unroll
  for (int mi = 0; mi < 2; ++mi)
#pragma unroll
    for (int ni = 0; ni < 4; ++ni)
#pragma unroll
      for (int r = 0; r < 4; ++r) {
        int qq = q0 + w * 32 + mi * 16 + lhi * 4 + r;
        long s = (long)c * 512 + qq;
        int col = h * 64 + ni * 16 + l15;
        float o = acc_o[mi][ni][r] / acc_l[mi][r];
        out[s * 1024 + col] = f2bf(o);
      }
}

extern "C" void kernel_launch(void* const* d_in, const int* in_sizes, int n_in,
                              void* d_out, int out_size, void* d_ws, size_t ws_size,
                              hipStream_t stream) {
  const float* x = (const float*)d_in[0];      // [4096][1024]
  const float* w_qkv = (const float*)d_in[1];  // [1024][3072]
  const float* w_out = (const float*)d_in[2];  // [1024][1024]
  float* out = (float*)d_out;                  // [4096][1024]

  u16* xb = (u16*)d_ws;                        // 4096*1024
  u16* wqkvT = xb + 4096 * 1024;               // [3072][1024]
  u16* woutT = wqkvT + 3072 * 1024;            // [1024][1024]
  u16* qh = woutT + 1024 * 1024;               // [16][4096][64]
  u16* kh = qh + 16 * 4096 * 64;
  u16* vh = kh + 16 * 4096 * 64;
  u16* attn = xb;  // alias: x_bf16 dead after GEMM1  (total ws = 40 MB)

  cast_f32_to_bf16<<<2048, 256, 0, stream>>>(x, xb, 4096 * 1024 / 8);
  transpose_cast<<<dim3(96, 32), 256, 0, stream>>>(w_qkv, wqkvT, 1024, 3072);
  transpose_cast<<<dim3(32, 32), 256, 0, stream>>>(w_out, woutT, 1024, 1024);

  gemm_bf16<1><<<dim3(24, 32), 256, 0, stream>>>(xb, wqkvT, nullptr, qh, kh, vh,
                                                 4096, 3072, 1024);
  attn_kernel<<<512, 256, 0, stream>>>(qh, kh, vh, attn);
  gemm_bf16<0><<<dim3(8, 32), 256, 0, stream>>>(attn, woutT, out, nullptr, nullptr, nullptr,
                                                4096, 1024, 1024);
}